// Round 11
// baseline (608.514 us; speedup 1.0000x reference)
//
#include <hip/hip_runtime.h>
#include <hip/hip_fp16.h>
#include <math.h>

#define H_HEADS 8
#define C_HID 32
#define D2 256
#define NEG_SLOPE 0.2f
#define KSTEPS 8

__device__ __forceinline__ float lrelu(float x) { return x < 0.f ? NEG_SLOPE * x : x; }
__device__ __forceinline__ float sigmoidf(float x) { return 1.f / (1.f + expf(-x)); }

// ---------------- init: zero counts/fill/embp, compute Pvec ----------------

__global__ void zero_all_kernel(int* counts, int* fill, double* embp, int KN, int NEMBP,
                                const float* __restrict__ W1, const float* __restrict__ a_src1,
                                const float* __restrict__ a_dst1, float* Pvec, int D1) {
    int tid = blockIdx.x * blockDim.x + threadIdx.x;
    if (tid < KN) { counts[tid] = 0; fill[tid] = 0; }
    if (tid < NEMBP) embp[tid] = 0.0;
    if (blockIdx.x == 0 && threadIdx.x < 16 && D1 == 1) {
        int h = threadIdx.x & 7;
        const float* a = (threadIdx.x >= 8) ? a_dst1 : a_src1;
        float s = 0.f;
        for (int c = 0; c < 32; ++c) s += W1[h * 32 + c] * a[h * 32 + c];
        Pvec[threadIdx.x] = s;
    }
}

// ---------------- batched CSR build (snapshot->XCD swizzled 1-D grids) ----------------

__global__ void count_all_kernel(const int* __restrict__ ei, int E, int N, int K,
                                 int* __restrict__ counts) {
    int bid = blockIdx.x;
    int k = bid % K;
    int jb = bid / K;
    int j = jb * blockDim.x + threadIdx.x;
    if (j >= E + N) return;
    int d = (j < E) ? ei[(size_t)k * 2 * E + E + j] : (j - E);
    atomicAdd(&counts[(size_t)k * N + d], 1);
}

__global__ __launch_bounds__(1024) void scan_all_kernel(const int* __restrict__ counts,
                                                        int* __restrict__ row_ptr, int N) {
    int k = blockIdx.x;
    const int* cnt = counts + (size_t)k * N;
    int* rp = row_ptr + (size_t)k * (N + 1);
    __shared__ int part[1024];
    int t = threadIdx.x;
    int ipt = (N + 1023) >> 10;
    int begin = t * ipt;
    int end = begin + ipt; if (end > N) end = N;
    if (begin > N) begin = N;
    int s = 0;
    for (int i = begin; i < end; ++i) s += cnt[i];
    part[t] = s;
    __syncthreads();
    for (int d = 1; d < 1024; d <<= 1) {
        int v = 0;
        if (t >= d) v = part[t - d];
        __syncthreads();
        if (t >= d) part[t] += v;
        __syncthreads();
    }
    int run = (t == 0) ? 0 : part[t - 1];
    for (int i = begin; i < end; ++i) { rp[i] = run; run += cnt[i]; }
    if (t == 1023) rp[N] = part[1023];
}

__global__ void scatter_all_kernel(const int* __restrict__ ei, int E, int N, int K,
                                   const int* __restrict__ row_ptr, int* __restrict__ fill,
                                   int* __restrict__ ein) {
    int bid = blockIdx.x;
    int k = bid % K;
    int jb = bid / K;
    int j = jb * blockDim.x + threadIdx.x;
    if (j >= E + N) return;
    int s, d;
    if (j < E) { s = ei[(size_t)k * 2 * E + j]; d = ei[(size_t)k * 2 * E + E + j]; }
    else { s = j - E; d = s; }
    int pos = row_ptr[(size_t)k * (N + 1) + d] + atomicAdd(&fill[(size_t)k * N + d], 1);
    ein[(size_t)k * (E + N) + pos] = s;
}

// ---------------- layer-1 rank-1 GAT (D1 == 1): writes S[n][8] only ----------------

__global__ __launch_bounds__(256) void agg1s_all_kernel(const float* __restrict__ xs,
                                                        const float* __restrict__ P,
                                                        const int* __restrict__ row_ptr,
                                                        const int* __restrict__ ein,
                                                        float* __restrict__ Sbuf,
                                                        int N, int E2, int k0, int BKcur) {
    int bid = blockIdx.x;
    int kb = bid % BKcur;
    int nb = bid / BKcur;
    int k = k0 + kb;
    const float* x = xs + (size_t)k * N;
    const int* rp = row_ptr + (size_t)k * (N + 1);
    const int* ek = ein + (size_t)k * E2;

    int n = nb * 4 + (threadIdx.x >> 6);
    if (n >= N) return;
    int lane = threadIdx.x & 63;
    int e0 = rp[n], e1 = rp[n + 1];
    int h8 = lane & 7;
    float Ps = P[h8], Pd = P[8 + h8];
    float base = x[n] * Pd;

    float mx = -INFINITY;
    for (int i = e0 + (lane >> 3); i < e1; i += 8) {
        float xv = x[ek[i]];
        mx = fmaxf(mx, lrelu(xv * Ps + base));
    }
    mx = fmaxf(mx, __shfl_xor(mx, 8));
    mx = fmaxf(mx, __shfl_xor(mx, 16));
    mx = fmaxf(mx, __shfl_xor(mx, 32));

    float num = 0.f, den = 0.f;
    for (int i = e0 + (lane >> 3); i < e1; i += 8) {
        float xv = x[ek[i]];
        float w = expf(lrelu(xv * Ps + base) - mx);
        num += w * xv;
        den += w;
    }
    num += __shfl_xor(num, 8);  den += __shfl_xor(den, 8);
    num += __shfl_xor(num, 16); den += __shfl_xor(den, 16);
    num += __shfl_xor(num, 32); den += __shfl_xor(den, 32);
    float S = num / (den + 1e-16f);

    if (lane < 8) Sbuf[((size_t)kb * N + n) * 8 + lane] = S;
}

// ---------------- generic layer-1 fallback (D1 != 1) ----------------

__global__ void h1_kernel(const float* __restrict__ x, const float* __restrict__ W,
                          float* __restrict__ h, int N, int D1) {
    int tid = blockIdx.x * blockDim.x + threadIdx.x;
    if (tid >= N * 256) return;
    int n = tid >> 8, j = tid & 255;
    float acc = 0.f;
    for (int d = 0; d < D1; ++d) acc += x[n * D1 + d] * W[d * 256 + j];
    h[tid] = acc;
}

// f32 attention scalars (fallback layer-1)
__global__ __launch_bounds__(256) void s_all_kernel(const float* __restrict__ bufA,
                                                    const float* __restrict__ a_src,
                                                    const float* __restrict__ a_dst,
                                                    float* __restrict__ s_src,
                                                    float* __restrict__ s_dst, int N) {
    int kb = blockIdx.y;
    int j = blockIdx.x * 256 + threadIdx.x;
    if (j >= N * 8) return;
    int n = j >> 3, hh = j & 7;
    const float* hp = bufA + (size_t)kb * N * 256 + (size_t)n * 256 + hh * 32;
    const float* as = a_src + hh * 32;
    const float* ad = a_dst + hh * 32;
    float ss = 0.f, sd = 0.f;
#pragma unroll
    for (int c = 0; c < 32; ++c) { float v = hp[c]; ss += v * as[c]; sd += v * ad[c]; }
    s_src[(size_t)kb * N * 8 + j] = ss;
    s_dst[(size_t)kb * N * 8 + j] = sd;
}

// fp16 attention scalars (fast path layer-2)
__global__ __launch_bounds__(256) void s_all_h16_kernel(const __half* __restrict__ h16,
                                                        const float* __restrict__ a_src,
                                                        const float* __restrict__ a_dst,
                                                        float* __restrict__ s_src,
                                                        float* __restrict__ s_dst, int N) {
    int kb = blockIdx.y;
    int j = blockIdx.x * 256 + threadIdx.x;
    if (j >= N * 8) return;
    int n = j >> 3, hh = j & 7;
    const __half2* hp = (const __half2*)(h16 + (size_t)kb * N * 256 + (size_t)n * 256 + hh * 32);
    const float* as = a_src + hh * 32;
    const float* ad = a_dst + hh * 32;
    float ss = 0.f, sd = 0.f;
#pragma unroll
    for (int c = 0; c < 16; ++c) {
        float2 v = __half22float2(hp[c]);
        ss += v.x * as[2 * c] + v.y * as[2 * c + 1];
        sd += v.x * ad[2 * c] + v.y * ad[2 * c + 1];
    }
    s_src[(size_t)kb * N * 8 + j] = ss;
    s_dst[(size_t)kb * N * 8 + j] = sd;
}

// fallback layer-1 full aggregation with output write (f32)
__global__ __launch_bounds__(256) void agg2_out_kernel(const float* __restrict__ h,
                                                       const float* __restrict__ s_src,
                                                       const float* __restrict__ s_dst,
                                                       const int* __restrict__ row_ptr,
                                                       const int* __restrict__ ein,
                                                       const float* __restrict__ bias,
                                                       float* __restrict__ out,
                                                       int N, int E2, int k0) {
    int k = k0;
    const int* rp = row_ptr + (size_t)k * (N + 1);
    const int* ek = ein + (size_t)k * E2;
    int n = blockIdx.x * 4 + (threadIdx.x >> 6);
    if (n >= N) return;
    int lane = threadIdx.x & 63;
    int e0 = rp[n], e1 = rp[n + 1];
    int h8 = lane & 7;
    float sd8 = s_dst[n * 8 + h8];

    float mx = -INFINITY;
    for (int i = e0 + (lane >> 3); i < e1; i += 8) {
        int s = ek[i];
        mx = fmaxf(mx, lrelu(s_src[s * 8 + h8] + sd8));
    }
    mx = fmaxf(mx, __shfl_xor(mx, 8));
    mx = fmaxf(mx, __shfl_xor(mx, 16));
    mx = fmaxf(mx, __shfl_xor(mx, 32));

    int hd = lane >> 3;
    float m = __shfl(mx, hd);
    float sdh = __shfl(sd8, hd);

    float den = 0.f;
    float4 acc = make_float4(0.f, 0.f, 0.f, 0.f);
    for (int i = e0; i < e1; ++i) {
        int s = ek[i];
        const float4 hv = *(const float4*)(h + (size_t)s * 256 + lane * 4);
        float w = expf(lrelu(s_src[s * 8 + hd] + sdh) - m);
        den += w;
        acc.x += w * hv.x; acc.y += w * hv.y; acc.z += w * hv.z; acc.w += w * hv.w;
    }
    float dE = den + 1e-16f;
    const float4 bv = *(const float4*)(bias + lane * 4);
    float4 o;
    o.x = fmaxf(acc.x / dE + bv.x, 0.f);
    o.y = fmaxf(acc.y / dE + bv.y, 0.f);
    o.z = fmaxf(acc.z / dE + bv.z, 0.f);
    o.w = fmaxf(acc.w / dE + bv.w, 0.f);
    *(float4*)(out + (size_t)n * 256 + lane * 4) = o;
}

// f32 -> fp16 convert (fallback path feeder)
__global__ void cvt_kernel(const float* __restrict__ src, __half* __restrict__ dst, int total) {
    int i = blockIdx.x * blockDim.x + threadIdx.x;
    if (i * 2 + 1 < total) {
        float2 v = *(const float2*)(src + i * 2);
        ((__half2*)dst)[i] = __floats2half2_rn(v.x, v.y);
    }
}

// ---------------- layer-2: per-node-head max (pass 1), writes mx[n][8] ----------------

__global__ __launch_bounds__(256) void aggmax_kernel(const float* __restrict__ s_src,
                                                     const float* __restrict__ s_dst,
                                                     const int* __restrict__ row_ptr,
                                                     const int* __restrict__ ein,
                                                     float* __restrict__ mxbuf,
                                                     int N, int E2, int k0, int BKcur) {
    int bid = blockIdx.x;
    int kb = bid % BKcur;
    int nb = bid / BKcur;
    int k = k0 + kb;
    int n = nb * 4 + (threadIdx.x >> 6);
    if (n >= N) return;
    int lane = threadIdx.x & 63;
    const float* ssrc = s_src + (size_t)kb * N * 8;
    const float* sdst = s_dst + (size_t)kb * N * 8;
    const int* rp = row_ptr + (size_t)k * (N + 1);
    const int* ek = ein + (size_t)k * E2;

    int e0 = rp[n], e1 = rp[n + 1];
    int h8 = lane & 7;
    float sd8 = sdst[n * 8 + h8];

    float mx = -INFINITY;
    for (int i = e0 + (lane >> 3); i < e1; i += 8) {
        int s = ek[i];
        mx = fmaxf(mx, lrelu(ssrc[s * 8 + h8] + sd8));
    }
    mx = fmaxf(mx, __shfl_xor(mx, 8));
    mx = fmaxf(mx, __shfl_xor(mx, 16));
    mx = fmaxf(mx, __shfl_xor(mx, 32));

    if (lane < 8) mxbuf[((size_t)kb * N + n) * 8 + lane] = mx;
}

// ---------------- layer-2: gather (fp16 rows, per-lane w recompute) + f64 mean-pool ----
// No shuffles: lane (hd = lane>>3) recomputes w for its head from L2-resident s_src —
// the 8x redundant v_exp is one wave-wide trans-pipe inst/edge, off the critical path.
// Edge order, w values, and accumulation order are bit-identical to R9's kernel.

__global__ __launch_bounds__(256) void aggpool_kernel(const __half* __restrict__ h16,
                                                      const float* __restrict__ s_src,
                                                      const float* __restrict__ s_dst,
                                                      const float* __restrict__ mxbuf,
                                                      const int* __restrict__ row_ptr,
                                                      const int* __restrict__ ein,
                                                      const float* __restrict__ bias,
                                                      double* __restrict__ embp,
                                                      int N, int E2, int k0, int BKcur) {
    int bid = blockIdx.x;
    int kb = bid % BKcur;
    int nb = bid / BKcur;
    int k = k0 + kb;
    int w = threadIdx.x >> 6;
    int lane = threadIdx.x & 63;
    int n = nb * 4 + w;
    bool active = (n < N);
    const __half* h = h16 + (size_t)kb * N * 256;
    const float* ssrc = s_src + (size_t)kb * N * 8;
    const float* sdst = s_dst + (size_t)kb * N * 8;
    const int* rp = row_ptr + (size_t)k * (N + 1);
    const int* ek = ein + (size_t)k * E2;

    float4 o = make_float4(0.f, 0.f, 0.f, 0.f);
    if (active) {
        int e0 = rp[n], e1 = rp[n + 1];
        int hd = lane >> 3;
        float m = mxbuf[((size_t)kb * N + n) * 8 + hd];
        float sdh = sdst[n * 8 + hd];

        float den = 0.f;
        float4 acc = make_float4(0.f, 0.f, 0.f, 0.f);
        for (int i = e0; i < e1; ++i) {
            int sj = ek[i];
            float ss = ssrc[sj * 8 + hd];
            float wj = expf(lrelu(ss + sdh) - m);
            const __half2* hp = (const __half2*)(h + (size_t)sj * 256 + lane * 4);
            float2 f0 = __half22float2(hp[0]);
            float2 f1 = __half22float2(hp[1]);
            den += wj;
            acc.x += wj * f0.x;
            acc.y += wj * f0.y;
            acc.z += wj * f1.x;
            acc.w += wj * f1.y;
        }
        float dE = den + 1e-16f;
        const float4 bv = *(const float4*)(bias + lane * 4);
        o.x = fmaxf(acc.x / dE + bv.x, 0.f);
        o.y = fmaxf(acc.y / dE + bv.y, 0.f);
        o.z = fmaxf(acc.z / dE + bv.z, 0.f);
        o.w = fmaxf(acc.w / dE + bv.w, 0.f);
    }

    __shared__ double pe[4][256];
    pe[w][lane * 4 + 0] = (double)o.x;
    pe[w][lane * 4 + 1] = (double)o.y;
    pe[w][lane * 4 + 2] = (double)o.z;
    pe[w][lane * 4 + 3] = (double)o.w;
    __syncthreads();
    int tid = threadIdx.x;
    double s = pe[0][tid] + pe[1][tid] + pe[2][tid] + pe[3][tid];
    atomicAdd(&embp[((size_t)k * 32 + (nb & 31)) * 256 + tid], s);
}

// ---------------- fused rank-1-A fp32 GEMM -> fp16 out: C16 = relu(S.W1+b1) * W2 ----------------

__global__ __launch_bounds__(256) void gemm_fused_kernel(const float* __restrict__ S,
                                                         const float* __restrict__ W1,
                                                         const float* __restrict__ bias1,
                                                         const float* __restrict__ B,
                                                         __half* __restrict__ C16, int M) {
    __shared__ float Ast[16][132];
    __shared__ float Bs[16][132];
    __shared__ float w1s[256], b1s[256];
    __shared__ float Ss[128 * 8];
    int tid = threadIdx.x;
    int bm = blockIdx.x, bn = blockIdx.y;

    w1s[tid] = W1[tid];
    b1s[tid] = bias1[tid];
    {
        int base = bm * 128 * 8 + tid * 4;
        float4 sv = make_float4(0.f, 0.f, 0.f, 0.f);
        if (bm * 128 + (tid * 4) / 8 < M) {
            sv = *(const float4*)(S + base);
        }
        *(float4*)&Ss[tid * 4] = sv;
    }

    int arow = tid >> 1;
    int kgrp = (tid & 1) * 8;
    bool rowvalid = (bm * 128 + arow < M);

    int brow = tid >> 4;
    int bcol = (tid & 15) * 8;
    const float* Bbase = B + bn * 128;

    int w = tid >> 6, lane = tid & 63;
    int qr = (w >> 1) * 64, qc = (w & 1) * 64;
    int ty = lane >> 3, tx = lane & 7;
    int r0 = qr + ty * 8, c0 = qc + tx * 8;
    float acc[8][8] = {};

    __syncthreads();

    for (int kt = 0; kt < 256; kt += 16) {
        float sh = Ss[arow * 8 + (kt >> 5)];
#pragma unroll
        for (int j = 0; j < 8; ++j) {
            int kk = kgrp + j;
            float a = fmaxf(fmaf(sh, w1s[kt + kk], b1s[kt + kk]), 0.f);
            Ast[kk][arow] = rowvalid ? a : 0.f;
        }
        const float* bg = Bbase + (size_t)(kt + brow) * 256 + bcol;
        *(float4*)&Bs[brow][bcol] = *(const float4*)bg;
        *(float4*)&Bs[brow][bcol + 4] = *(const float4*)(bg + 4);
        __syncthreads();
#pragma unroll
        for (int kk = 0; kk < 16; ++kk) {
            float4 a0 = *(const float4*)&Ast[kk][r0];
            float4 a1 = *(const float4*)&Ast[kk][r0 + 4];
            float4 b0 = *(const float4*)&Bs[kk][c0];
            float4 b1v = *(const float4*)&Bs[kk][c0 + 4];
            float ar[8] = {a0.x, a0.y, a0.z, a0.w, a1.x, a1.y, a1.z, a1.w};
            float br[8] = {b0.x, b0.y, b0.z, b0.w, b1v.x, b1v.y, b1v.z, b1v.w};
#pragma unroll
            for (int i2 = 0; i2 < 8; ++i2)
#pragma unroll
                for (int j2 = 0; j2 < 8; ++j2) acc[i2][j2] += ar[i2] * br[j2];
        }
        __syncthreads();
    }
#pragma unroll
    for (int i2 = 0; i2 < 8; ++i2) {
        int gm = bm * 128 + r0 + i2;
        if (gm < M) {
            float4 pack;
            ((__half2*)&pack)[0] = __floats2half2_rn(acc[i2][0], acc[i2][1]);
            ((__half2*)&pack)[1] = __floats2half2_rn(acc[i2][2], acc[i2][3]);
            ((__half2*)&pack)[2] = __floats2half2_rn(acc[i2][4], acc[i2][5]);
            ((__half2*)&pack)[3] = __floats2half2_rn(acc[i2][6], acc[i2][7]);
            *(float4*)(C16 + (size_t)gm * 256 + bn * 128 + c0) = pack;
        }
    }
}

// ---------------- plain fp32 GEMM (fallback path) ----------------

__global__ __launch_bounds__(256) void gemm_kernel(const float* __restrict__ A,
                                                   const float* __restrict__ B,
                                                   float* __restrict__ C, int M) {
    __shared__ float Ast[8][132];
    __shared__ float Bs[8][128];
    int tid = threadIdx.x;
    int bm = blockIdx.x, bn = blockIdx.y;
    int ty = tid >> 4, tx = tid & 15;
    int r0 = ty * 8, c0 = tx * 8;
    float acc[8][8] = {};
    int arow = tid >> 1, acol = (tid & 1) * 4;
    int brow = tid >> 5, bcol = (tid & 31) * 4;
    const float* Bbase = B + bn * 128;

    for (int kt = 0; kt < 256; kt += 8) {
        int gr = bm * 128 + arow;
        float4 av = (gr < M) ? *(const float4*)(A + (size_t)gr * 256 + kt + acol)
                             : make_float4(0.f, 0.f, 0.f, 0.f);
        Ast[acol + 0][arow] = av.x;
        Ast[acol + 1][arow] = av.y;
        Ast[acol + 2][arow] = av.z;
        Ast[acol + 3][arow] = av.w;
        *(float4*)&Bs[brow][bcol] = *(const float4*)(Bbase + (size_t)(kt + brow) * 256 + bcol);
        __syncthreads();
#pragma unroll
        for (int kk = 0; kk < 8; ++kk) {
            float4 a0 = *(const float4*)&Ast[kk][r0];
            float4 a1 = *(const float4*)&Ast[kk][r0 + 4];
            float4 b0 = *(const float4*)&Bs[kk][c0];
            float4 b1 = *(const float4*)&Bs[kk][c0 + 4];
            float ar[8] = {a0.x, a0.y, a0.z, a0.w, a1.x, a1.y, a1.z, a1.w};
            float br[8] = {b0.x, b0.y, b0.z, b0.w, b1.x, b1.y, b1.z, b1.w};
#pragma unroll
            for (int i2 = 0; i2 < 8; ++i2)
#pragma unroll
                for (int j2 = 0; j2 < 8; ++j2) acc[i2][j2] += ar[i2] * br[j2];
        }
        __syncthreads();
    }
#pragma unroll
    for (int i2 = 0; i2 < 8; ++i2) {
        int gm = bm * 128 + r0 + i2;
        if (gm < M) {
            *(float4*)(C + (size_t)gm * 256 + bn * 128 + c0) =
                make_float4(acc[i2][0], acc[i2][1], acc[i2][2], acc[i2][3]);
            *(float4*)(C + (size_t)gm * 256 + bn * 128 + c0 + 4) =
                make_float4(acc[i2][4], acc[i2][5], acc[i2][6], acc[i2][7]);
        }
    }
}

// ---------------- merge f64 pool partials -> f32 emb; zero LSTM flags ----------------

__global__ void merge_kernel(const double* __restrict__ embp, float* __restrict__ emb,
                             int* __restrict__ flags) {
    int k = blockIdx.x, c = threadIdx.x;
    double s = 0.0;
#pragma unroll
    for (int p = 0; p < 32; ++p) s += embp[((size_t)k * 32 + p) * 256 + c];
    emb[k * 256 + c] = (float)s;
    if (blockIdx.x == 0 && threadIdx.x < 2 * (KSTEPS + 1)) flags[threadIdx.x] = 0;
}

// ---------------- bidirectional LSTM ----------------

__global__ __launch_bounds__(256) void lstm_rec_kernel(
    const float* __restrict__ emb, float invN,
    const float* __restrict__ Wih_f, const float* __restrict__ Whh_f,
    const float* __restrict__ bih_f, const float* __restrict__ bhh_f,
    const float* __restrict__ Wih_b, const float* __restrict__ Whh_b,
    const float* __restrict__ bih_b, const float* __restrict__ bhh_b,
    float* __restrict__ hbuf, int* __restrict__ flags, float* __restrict__ out) {
    int dir = blockIdx.x >> 4;
    int seg = blockIdx.x & 15;
    const float* Wih = dir ? Wih_b : Wih_f;
    const float* Whh = dir ? Whh_b : Whh_f;
    const float* bih = dir ? bih_b : bih_f;
    const float* bhh = dir ? bhh_b : bhh_f;

    __shared__ float wh[64 * 256];
    __shared__ float wi[64 * 256];
    __shared__ float xs_s[KSTEPS * 256];
    __shared__ float gx[KSTEPS][64];
    __shared__ float garr[64];
    __shared__ float hprev_s[256];
    int tid = threadIdx.x;

    for (int v = tid; v < 64 * 64; v += 256) {
        int lrow = v >> 6;
        int c4 = (v & 63) * 4;
        int grow = ((lrow >> 4) << 8) + seg * 16 + (lrow & 15);
        *(float4*)&wh[lrow * 256 + c4] = *(const float4*)(Whh + (size_t)grow * 256 + c4);
        *(float4*)&wi[lrow * 256 + c4] = *(const float4*)(Wih + (size_t)grow * 256 + c4);
    }
    for (int idx = tid; idx < KSTEPS * 256; idx += 256) xs_s[idx] = emb[idx] * invN;
    __syncthreads();

    for (int d = tid; d < KSTEPS * 64; d += 256) {
        int st = d >> 6, lr = d & 63;
        const float* wr = &wi[lr << 8];
        const float* xr = &xs_s[st << 8];
        int r = (tid & 63) << 2;
        float acc = 0.f;
#pragma unroll 8
        for (int kk = 0; kk < 256; kk += 4) {
            int k2 = (kk + r) & 255;
            acc += wr[k2] * xr[k2] + wr[k2 + 1] * xr[k2 + 1] +
                   wr[k2 + 2] * xr[k2 + 2] + wr[k2 + 3] * xr[k2 + 3];
        }
        int grow = ((lr >> 4) << 8) + seg * 16 + (lr & 15);
        gx[st][lr] = acc + bih[grow] + bhh[grow];
    }

    int* flag = flags + dir * (KSTEPS + 1);
    float* hb = hbuf + dir * (KSTEPS + 1) * 256;

    if (tid < 16)
        __hip_atomic_store(&hb[seg * 16 + tid], 0.f, __ATOMIC_RELAXED, __HIP_MEMORY_SCOPE_AGENT);
    __syncthreads();
    if (tid == 0)
        __hip_atomic_fetch_add(&flag[0], 1, __ATOMIC_RELEASE, __HIP_MEMORY_SCOPE_AGENT);

    float c_reg = 0.f;

    for (int step = 0; step < KSTEPS; ++step) {
        if (tid == 0) {
            while (__hip_atomic_load(&flag[step], __ATOMIC_RELAXED, __HIP_MEMORY_SCOPE_AGENT) < 16) {
                __builtin_amdgcn_s_sleep(1);
            }
            (void)__hip_atomic_load(&flag[step], __ATOMIC_ACQUIRE, __HIP_MEMORY_SCOPE_AGENT);
        }
        __syncthreads();
        hprev_s[tid] = __hip_atomic_load(&hb[step * 256 + tid], __ATOMIC_RELAXED,
                                         __HIP_MEMORY_SCOPE_AGENT);
        __syncthreads();

        int d = tid >> 2, p = tid & 3;
        const float* wr = &wh[(d << 8) + (p << 6)];
        const float* hr = &hprev_s[p << 6];
        int rot = tid & 63;
        float acc = 0.f;
#pragma unroll 8
        for (int k = 0; k < 64; ++k) {
            int k2 = (k + rot) & 63;
            acc += wr[k2] * hr[k2];
        }
        acc += __shfl_xor(acc, 1);
        acc += __shfl_xor(acc, 2);
        if (p == 0) garr[d] = acc;
        __syncthreads();

        if (tid < 16) {
            float ig = sigmoidf(garr[tid] + gx[step][tid]);
            float fg = sigmoidf(garr[16 + tid] + gx[step][16 + tid]);
            float gg = tanhf(garr[32 + tid] + gx[step][32 + tid]);
            float og = sigmoidf(garr[48 + tid] + gx[step][48 + tid]);
            float cn = fg * c_reg + ig * gg;
            c_reg = cn;
            float hn = og * tanhf(cn);
            __hip_atomic_store(&hb[(step + 1) * 256 + seg * 16 + tid], hn, __ATOMIC_RELAXED,
                               __HIP_MEMORY_SCOPE_AGENT);
        }
        __syncthreads();
        if (tid == 0)
            __hip_atomic_fetch_add(&flag[step + 1], 1, __ATOMIC_RELEASE, __HIP_MEMORY_SCOPE_AGENT);
    }

    if (tid < 16)
        out[dir * 256 + seg * 16 + tid] =
            __hip_atomic_load(&hb[KSTEPS * 256 + seg * 16 + tid], __ATOMIC_RELAXED,
                              __HIP_MEMORY_SCOPE_AGENT);
}

// ---------------- launch ----------------

extern "C" void kernel_launch(void* const* d_in, const int* in_sizes, int n_in,
                              void* d_out, int out_size, void* d_ws, size_t ws_size,
                              hipStream_t stream) {
    const float* xs = (const float*)d_in[0];
    const int* edge_index = (const int*)d_in[1];
    const float* W1 = (const float*)d_in[2];
    const float* a_src1 = (const float*)d_in[3];
    const float* a_dst1 = (const float*)d_in[4];
    const float* b1 = (const float*)d_in[5];
    const float* W2 = (const float*)d_in[6];
    const float* a_src2 = (const float*)d_in[7];
    const float* a_dst2 = (const float*)d_in[8];
    const float* b2 = (const float*)d_in[9];
    const float* Wih_f = (const float*)d_in[10];
    const float* Whh_f = (const float*)d_in[11];
    const float* bih_f = (const float*)d_in[12];
    const float* bhh_f = (const float*)d_in[13];
    const float* Wih_b = (const float*)d_in[14];
    const float* Whh_b = (const float*)d_in[15];
    const float* bih_b = (const float*)d_in[16];
    const float* bhh_b = (const float*)d_in[17];

    const int K = KSTEPS;
    int D1 = in_sizes[2] / D2;
    int N = in_sizes[0] / (K * D1);
    int E = in_sizes[1] / (2 * K);
    int E2 = E + N;

    auto al = [](size_t x) { return (x + 255) & ~(size_t)255; };
    size_t fixed_sz = al((size_t)K * N * 4)
                    + al((size_t)K * (N + 1) * 4)
                    + al((size_t)K * N * 4)
                    + al((size_t)K * E2 * 4)
                    + al((size_t)K * 32 * 256 * 8)
                    + al((size_t)K * 256 * 4)
                    + al((size_t)2 * (K + 1) * 256 * 4)
                    + al((size_t)2 * (K + 1) * 4)
                    + al(16 * 4);
    int BK = 8;
    while (BK > 1) {
        size_t need = fixed_sz + 4 * al((size_t)BK * N * 8 * 4) + 2 * al((size_t)BK * N * 256 * 4);
        if (need <= ws_size) break;
        BK >>= 1;
    }

    char* w = (char*)d_ws;
    auto alloc = [&](size_t bytes) { char* p = w; w += (bytes + 255) & ~(size_t)255; return p; };
    int* counts = (int*)alloc((size_t)K * N * 4);
    int* row_ptr = (int*)alloc((size_t)K * (N + 1) * 4);
    int* fill = (int*)alloc((size_t)K * N * 4);
    int* ein = (int*)alloc((size_t)K * E2 * 4);
    double* embp = (double*)alloc((size_t)K * 32 * 256 * 8);
    float* emb = (float*)alloc((size_t)K * 256 * 4);
    float* hbuf = (float*)alloc((size_t)2 * (K + 1) * 256 * 4);
    int* flags = (int*)alloc((size_t)2 * (K + 1) * 4);
    float* Pvec = (float*)alloc(16 * 4);
    float* Sbuf = (float*)alloc((size_t)BK * N * 8 * 4);
    float* s_src = (float*)alloc((size_t)BK * N * 8 * 4);
    float* s_dst = (float*)alloc((size_t)BK * N * 8 * 4);
    float* mxbuf = (float*)alloc((size_t)BK * N * 8 * 4);
    float* bufA = (float*)alloc((size_t)BK * N * 256 * 4);
    float* bufB = (float*)alloc((size_t)BK * N * 256 * 4);
    __half* h16 = (__half*)bufA;     // fast path
    __half* h16_fb = (__half*)bufB;  // fallback path

    int KN = K * N;
    int NEMBP = K * 32 * 256;
    int zblk = ((KN > NEMBP ? KN : NEMBP) + 255) / 256;
    zero_all_kernel<<<zblk, 256, 0, stream>>>(counts, fill, embp, KN, NEMBP,
                                              W1, a_src1, a_dst1, Pvec, D1);
    int eblk = (E2 + 255) / 256;
    count_all_kernel<<<eblk * K, 256, 0, stream>>>(edge_index, E, N, K, counts);
    scan_all_kernel<<<K, 1024, 0, stream>>>(counts, row_ptr, N);
    scatter_all_kernel<<<eblk * K, 256, 0, stream>>>(edge_index, E, N, K, row_ptr, fill, ein);

    int nblk4 = (N + 3) / 4;
    int sblk = (N * 8 + 255) / 256;
    for (int k0 = 0; k0 < K; k0 += BK) {
        int BKcur = (K - k0 < BK) ? (K - k0) : BK;
        if (D1 == 1) {
            agg1s_all_kernel<<<nblk4 * BKcur, 256, 0, stream>>>(
                xs, Pvec, row_ptr, ein, Sbuf, N, E2, k0, BKcur);
            int M = BKcur * N;
            gemm_fused_kernel<<<dim3((M + 127) / 128, 2), 256, 0, stream>>>(
                Sbuf, W1, b1, W2, h16, M);
            s_all_h16_kernel<<<dim3(sblk, BKcur), 256, 0, stream>>>(h16, a_src2, a_dst2,
                                                                    s_src, s_dst, N);
            aggmax_kernel<<<nblk4 * BKcur, 256, 0, stream>>>(
                s_src, s_dst, row_ptr, ein, mxbuf, N, E2, k0, BKcur);
            aggpool_kernel<<<nblk4 * BKcur, 256, 0, stream>>>(
                h16, s_src, s_dst, mxbuf, row_ptr, ein, b2, embp, N, E2, k0, BKcur);
        } else {
            for (int kk = 0; kk < BKcur; ++kk) {
                int k = k0 + kk;
                const float* xk = xs + (size_t)k * N * D1;
                h1_kernel<<<(N * 256 + 255) / 256, 256, 0, stream>>>(xk, W1, bufA, N, D1);
                s_all_kernel<<<dim3(sblk, 1), 256, 0, stream>>>(bufA, a_src1, a_dst1,
                                                                s_src, s_dst, N);
                agg2_out_kernel<<<nblk4, 256, 0, stream>>>(bufA, s_src, s_dst, row_ptr, ein,
                                                           b1, bufB, N, E2, k);
                gemm_kernel<<<dim3((N + 127) / 128, 2), 256, 0, stream>>>(bufB, W2, bufA, N);
                cvt_kernel<<<(N * 256 / 2 + 255) / 256, 256, 0, stream>>>(bufA, h16_fb, N * 256);
                s_all_h16_kernel<<<dim3(sblk, 1), 256, 0, stream>>>(h16_fb, a_src2, a_dst2,
                                                                    s_src, s_dst, N);
                aggmax_kernel<<<nblk4, 256, 0, stream>>>(
                    s_src, s_dst, row_ptr, ein, mxbuf, N, E2, k, 1);
                aggpool_kernel<<<nblk4, 256, 0, stream>>>(
                    h16_fb, s_src, s_dst, mxbuf, row_ptr, ein, b2, embp, N, E2, k, 1);
            }
        }
    }

    merge_kernel<<<K, 256, 0, stream>>>(embp, emb, flags);
    lstm_rec_kernel<<<32, 256, 0, stream>>>(emb, 1.f / (float)N,
                                            Wih_f, Whh_f, bih_f, bhh_f,
                                            Wih_b, Whh_b, bih_b, bhh_b,
                                            hbuf, flags, (float*)d_out);
}

// Round 12
// 543.422 us; speedup vs baseline: 1.1198x; 1.1198x over previous
//
#include <hip/hip_runtime.h>
#include <hip/hip_fp16.h>
#include <math.h>

#define H_HEADS 8
#define C_HID 32
#define D2 256
#define NEG_SLOPE 0.2f
#define KSTEPS 8

__device__ __forceinline__ float lrelu(float x) { return x < 0.f ? NEG_SLOPE * x : x; }
__device__ __forceinline__ float sigmoidf(float x) { return 1.f / (1.f + expf(-x)); }

// ---------------- init: zero counts/fill/embp, compute Pvec ----------------

__global__ void zero_all_kernel(int* counts, int* fill, double* embp, int KN, int NEMBP,
                                const float* __restrict__ W1, const float* __restrict__ a_src1,
                                const float* __restrict__ a_dst1, float* Pvec, int D1) {
    int tid = blockIdx.x * blockDim.x + threadIdx.x;
    if (tid < KN) { counts[tid] = 0; fill[tid] = 0; }
    if (tid < NEMBP) embp[tid] = 0.0;
    if (blockIdx.x == 0 && threadIdx.x < 16 && D1 == 1) {
        int h = threadIdx.x & 7;
        const float* a = (threadIdx.x >= 8) ? a_dst1 : a_src1;
        float s = 0.f;
        for (int c = 0; c < 32; ++c) s += W1[h * 32 + c] * a[h * 32 + c];
        Pvec[threadIdx.x] = s;
    }
}

// ---------------- batched CSR build (snapshot->XCD swizzled 1-D grids) ----------------

__global__ void count_all_kernel(const int* __restrict__ ei, int E, int N, int K,
                                 int* __restrict__ counts) {
    int bid = blockIdx.x;
    int k = bid % K;
    int jb = bid / K;
    int j = jb * blockDim.x + threadIdx.x;
    if (j >= E + N) return;
    int d = (j < E) ? ei[(size_t)k * 2 * E + E + j] : (j - E);
    atomicAdd(&counts[(size_t)k * N + d], 1);
}

__global__ __launch_bounds__(1024) void scan_all_kernel(const int* __restrict__ counts,
                                                        int* __restrict__ row_ptr, int N) {
    int k = blockIdx.x;
    const int* cnt = counts + (size_t)k * N;
    int* rp = row_ptr + (size_t)k * (N + 1);
    __shared__ int part[1024];
    int t = threadIdx.x;
    int ipt = (N + 1023) >> 10;
    int begin = t * ipt;
    int end = begin + ipt; if (end > N) end = N;
    if (begin > N) begin = N;
    int s = 0;
    for (int i = begin; i < end; ++i) s += cnt[i];
    part[t] = s;
    __syncthreads();
    for (int d = 1; d < 1024; d <<= 1) {
        int v = 0;
        if (t >= d) v = part[t - d];
        __syncthreads();
        if (t >= d) part[t] += v;
        __syncthreads();
    }
    int run = (t == 0) ? 0 : part[t - 1];
    for (int i = begin; i < end; ++i) { rp[i] = run; run += cnt[i]; }
    if (t == 1023) rp[N] = part[1023];
}

__global__ void scatter_all_kernel(const int* __restrict__ ei, int E, int N, int K,
                                   const int* __restrict__ row_ptr, int* __restrict__ fill,
                                   int* __restrict__ ein) {
    int bid = blockIdx.x;
    int k = bid % K;
    int jb = bid / K;
    int j = jb * blockDim.x + threadIdx.x;
    if (j >= E + N) return;
    int s, d;
    if (j < E) { s = ei[(size_t)k * 2 * E + j]; d = ei[(size_t)k * 2 * E + E + j]; }
    else { s = j - E; d = s; }
    int pos = row_ptr[(size_t)k * (N + 1) + d] + atomicAdd(&fill[(size_t)k * N + d], 1);
    ein[(size_t)k * (E + N) + pos] = s;
}

// ---------------- layer-1 rank-1 GAT (D1 == 1): writes S[n][8] only ----------------

__global__ __launch_bounds__(256) void agg1s_all_kernel(const float* __restrict__ xs,
                                                        const float* __restrict__ P,
                                                        const int* __restrict__ row_ptr,
                                                        const int* __restrict__ ein,
                                                        float* __restrict__ Sbuf,
                                                        int N, int E2, int k0, int BKcur) {
    int bid = blockIdx.x;
    int kb = bid % BKcur;
    int nb = bid / BKcur;
    int k = k0 + kb;
    const float* x = xs + (size_t)k * N;
    const int* rp = row_ptr + (size_t)k * (N + 1);
    const int* ek = ein + (size_t)k * E2;

    int n = nb * 4 + (threadIdx.x >> 6);
    if (n >= N) return;
    int lane = threadIdx.x & 63;
    int e0 = rp[n], e1 = rp[n + 1];
    int h8 = lane & 7;
    float Ps = P[h8], Pd = P[8 + h8];
    float base = x[n] * Pd;

    float mx = -INFINITY;
    for (int i = e0 + (lane >> 3); i < e1; i += 8) {
        float xv = x[ek[i]];
        mx = fmaxf(mx, lrelu(xv * Ps + base));
    }
    mx = fmaxf(mx, __shfl_xor(mx, 8));
    mx = fmaxf(mx, __shfl_xor(mx, 16));
    mx = fmaxf(mx, __shfl_xor(mx, 32));

    float num = 0.f, den = 0.f;
    for (int i = e0 + (lane >> 3); i < e1; i += 8) {
        float xv = x[ek[i]];
        float w = __expf(lrelu(xv * Ps + base) - mx);
        num += w * xv;
        den += w;
    }
    num += __shfl_xor(num, 8);  den += __shfl_xor(den, 8);
    num += __shfl_xor(num, 16); den += __shfl_xor(den, 16);
    num += __shfl_xor(num, 32); den += __shfl_xor(den, 32);
    float S = num / (den + 1e-16f);

    if (lane < 8) Sbuf[((size_t)kb * N + n) * 8 + lane] = S;
}

// ---------------- generic layer-1 fallback (D1 != 1) ----------------

__global__ void h1_kernel(const float* __restrict__ x, const float* __restrict__ W,
                          float* __restrict__ h, int N, int D1) {
    int tid = blockIdx.x * blockDim.x + threadIdx.x;
    if (tid >= N * 256) return;
    int n = tid >> 8, j = tid & 255;
    float acc = 0.f;
    for (int d = 0; d < D1; ++d) acc += x[n * D1 + d] * W[d * 256 + j];
    h[tid] = acc;
}

// f32 attention scalars (fallback layer-1)
__global__ __launch_bounds__(256) void s_all_kernel(const float* __restrict__ bufA,
                                                    const float* __restrict__ a_src,
                                                    const float* __restrict__ a_dst,
                                                    float* __restrict__ s_src,
                                                    float* __restrict__ s_dst, int N) {
    int kb = blockIdx.y;
    int j = blockIdx.x * 256 + threadIdx.x;
    if (j >= N * 8) return;
    int n = j >> 3, hh = j & 7;
    const float* hp = bufA + (size_t)kb * N * 256 + (size_t)n * 256 + hh * 32;
    const float* as = a_src + hh * 32;
    const float* ad = a_dst + hh * 32;
    float ss = 0.f, sd = 0.f;
#pragma unroll
    for (int c = 0; c < 32; ++c) { float v = hp[c]; ss += v * as[c]; sd += v * ad[c]; }
    s_src[(size_t)kb * N * 8 + j] = ss;
    s_dst[(size_t)kb * N * 8 + j] = sd;
}

// fp16 attention scalars (fast path layer-2)
__global__ __launch_bounds__(256) void s_all_h16_kernel(const __half* __restrict__ h16,
                                                        const float* __restrict__ a_src,
                                                        const float* __restrict__ a_dst,
                                                        float* __restrict__ s_src,
                                                        float* __restrict__ s_dst, int N) {
    int kb = blockIdx.y;
    int j = blockIdx.x * 256 + threadIdx.x;
    if (j >= N * 8) return;
    int n = j >> 3, hh = j & 7;
    const __half2* hp = (const __half2*)(h16 + (size_t)kb * N * 256 + (size_t)n * 256 + hh * 32);
    const float* as = a_src + hh * 32;
    const float* ad = a_dst + hh * 32;
    float ss = 0.f, sd = 0.f;
#pragma unroll
    for (int c = 0; c < 16; ++c) {
        float2 v = __half22float2(hp[c]);
        ss += v.x * as[2 * c] + v.y * as[2 * c + 1];
        sd += v.x * ad[2 * c] + v.y * ad[2 * c + 1];
    }
    s_src[(size_t)kb * N * 8 + j] = ss;
    s_dst[(size_t)kb * N * 8 + j] = sd;
}

// fallback layer-1 full aggregation with output write (f32)
__global__ __launch_bounds__(256) void agg2_out_kernel(const float* __restrict__ h,
                                                       const float* __restrict__ s_src,
                                                       const float* __restrict__ s_dst,
                                                       const int* __restrict__ row_ptr,
                                                       const int* __restrict__ ein,
                                                       const float* __restrict__ bias,
                                                       float* __restrict__ out,
                                                       int N, int E2, int k0) {
    int k = k0;
    const int* rp = row_ptr + (size_t)k * (N + 1);
    const int* ek = ein + (size_t)k * E2;
    int n = blockIdx.x * 4 + (threadIdx.x >> 6);
    if (n >= N) return;
    int lane = threadIdx.x & 63;
    int e0 = rp[n], e1 = rp[n + 1];
    int h8 = lane & 7;
    float sd8 = s_dst[n * 8 + h8];

    float mx = -INFINITY;
    for (int i = e0 + (lane >> 3); i < e1; i += 8) {
        int s = ek[i];
        mx = fmaxf(mx, lrelu(s_src[s * 8 + h8] + sd8));
    }
    mx = fmaxf(mx, __shfl_xor(mx, 8));
    mx = fmaxf(mx, __shfl_xor(mx, 16));
    mx = fmaxf(mx, __shfl_xor(mx, 32));

    int hd = lane >> 3;
    float m = __shfl(mx, hd);
    float sdh = __shfl(sd8, hd);

    float den = 0.f;
    float4 acc = make_float4(0.f, 0.f, 0.f, 0.f);
    for (int i = e0; i < e1; ++i) {
        int s = ek[i];
        const float4 hv = *(const float4*)(h + (size_t)s * 256 + lane * 4);
        float w = expf(lrelu(s_src[s * 8 + hd] + sdh) - m);
        den += w;
        acc.x += w * hv.x; acc.y += w * hv.y; acc.z += w * hv.z; acc.w += w * hv.w;
    }
    float dE = den + 1e-16f;
    const float4 bv = *(const float4*)(bias + lane * 4);
    float4 o;
    o.x = fmaxf(acc.x / dE + bv.x, 0.f);
    o.y = fmaxf(acc.y / dE + bv.y, 0.f);
    o.z = fmaxf(acc.z / dE + bv.z, 0.f);
    o.w = fmaxf(acc.w / dE + bv.w, 0.f);
    *(float4*)(out + (size_t)n * 256 + lane * 4) = o;
}

// f32 -> fp16 convert (fallback path feeder)
__global__ void cvt_kernel(const float* __restrict__ src, __half* __restrict__ dst, int total) {
    int i = blockIdx.x * blockDim.x + threadIdx.x;
    if (i * 2 + 1 < total) {
        float2 v = *(const float2*)(src + i * 2);
        ((__half2*)dst)[i] = __floats2half2_rn(v.x, v.y);
    }
}

// ---------------- layer-2 aggregation (fp16 gather) fused with f64 mean-pool ----------------
// R9 combined structure: chunked pass 2, w computed once per (edge,head) across the
// wave then broadcast via shuffle; exp via native __expf (2 instructions).

__global__ __launch_bounds__(256) void agg2pool_kernel(const __half* __restrict__ h16,
                                                       const float* __restrict__ s_src,
                                                       const float* __restrict__ s_dst,
                                                       const int* __restrict__ row_ptr,
                                                       const int* __restrict__ ein,
                                                       const float* __restrict__ bias,
                                                       double* __restrict__ embp,
                                                       int N, int E2, int k0, int BKcur) {
    int bid = blockIdx.x;
    int kb = bid % BKcur;
    int nb = bid / BKcur;
    int k = k0 + kb;
    int w = threadIdx.x >> 6;
    int lane = threadIdx.x & 63;
    int n = nb * 4 + w;
    bool active = (n < N);
    const __half* h = h16 + (size_t)kb * N * 256;
    const float* ssrc = s_src + (size_t)kb * N * 8;
    const float* sdst = s_dst + (size_t)kb * N * 8;
    const int* rp = row_ptr + (size_t)k * (N + 1);
    const int* ek = ein + (size_t)k * E2;

    float4 o = make_float4(0.f, 0.f, 0.f, 0.f);
    if (active) {
        int e0 = rp[n], e1 = rp[n + 1];
        int h8 = lane & 7;    // head for pass-1 / w-compute
        int es = lane >> 3;   // edge slot for w-compute
        int hd = lane >> 3;   // head for gather (cols lane*4..lane*4+3)
        float sd8 = sdst[n * 8 + h8];

        float mx = -INFINITY;
        for (int i = e0 + es; i < e1; i += 8) {
            int s = ek[i];
            mx = fmaxf(mx, lrelu(ssrc[s * 8 + h8] + sd8));
        }
        mx = fmaxf(mx, __shfl_xor(mx, 8));
        mx = fmaxf(mx, __shfl_xor(mx, 16));
        mx = fmaxf(mx, __shfl_xor(mx, 32));

        float den = 0.f;
        float4 acc = make_float4(0.f, 0.f, 0.f, 0.f);

        for (int c0 = e0; c0 < e1; c0 += 8) {
            int eI = c0 + es;
            bool valid = (eI < e1);
            int sA = ek[valid ? eI : e0];
            float wv = __expf(lrelu(ssrc[sA * 8 + h8] + sd8) - mx);
            if (!valid) wv = 0.f;

            int jmax = e1 - c0; if (jmax > 8) jmax = 8;
#pragma unroll 8
            for (int j = 0; j < 8; ++j) {
                if (j >= jmax) break;
                int srcLane = (j << 3) + hd;
                float wj = __shfl(wv, srcLane);
                int sj = __shfl(sA, srcLane);
                const __half2* hp = (const __half2*)(h + (size_t)sj * 256 + lane * 4);
                float2 f0 = __half22float2(hp[0]);
                float2 f1 = __half22float2(hp[1]);
                den += wj;
                acc.x += wj * f0.x;
                acc.y += wj * f0.y;
                acc.z += wj * f1.x;
                acc.w += wj * f1.y;
            }
        }
        float dE = den + 1e-16f;
        const float4 bv = *(const float4*)(bias + lane * 4);
        o.x = fmaxf(acc.x / dE + bv.x, 0.f);
        o.y = fmaxf(acc.y / dE + bv.y, 0.f);
        o.z = fmaxf(acc.z / dE + bv.z, 0.f);
        o.w = fmaxf(acc.w / dE + bv.w, 0.f);
    }

    __shared__ double pe[4][256];
    pe[w][lane * 4 + 0] = (double)o.x;
    pe[w][lane * 4 + 1] = (double)o.y;
    pe[w][lane * 4 + 2] = (double)o.z;
    pe[w][lane * 4 + 3] = (double)o.w;
    __syncthreads();
    int tid = threadIdx.x;
    double s = pe[0][tid] + pe[1][tid] + pe[2][tid] + pe[3][tid];
    atomicAdd(&embp[((size_t)k * 32 + (nb & 31)) * 256 + tid], s);
}

// ---------------- fused rank-1-A fp32 GEMM -> fp16 out: C16 = relu(S.W1+b1) * W2 ----------------

__global__ __launch_bounds__(256) void gemm_fused_kernel(const float* __restrict__ S,
                                                         const float* __restrict__ W1,
                                                         const float* __restrict__ bias1,
                                                         const float* __restrict__ B,
                                                         __half* __restrict__ C16, int M) {
    __shared__ float Ast[16][132];
    __shared__ float Bs[16][132];
    __shared__ float w1s[256], b1s[256];
    __shared__ float Ss[128 * 8];
    int tid = threadIdx.x;
    int bm = blockIdx.x, bn = blockIdx.y;

    w1s[tid] = W1[tid];
    b1s[tid] = bias1[tid];
    {
        int base = bm * 128 * 8 + tid * 4;
        float4 sv = make_float4(0.f, 0.f, 0.f, 0.f);
        if (bm * 128 + (tid * 4) / 8 < M) {
            sv = *(const float4*)(S + base);
        }
        *(float4*)&Ss[tid * 4] = sv;
    }

    int arow = tid >> 1;
    int kgrp = (tid & 1) * 8;
    bool rowvalid = (bm * 128 + arow < M);

    int brow = tid >> 4;
    int bcol = (tid & 15) * 8;
    const float* Bbase = B + bn * 128;

    int w = tid >> 6, lane = tid & 63;
    int qr = (w >> 1) * 64, qc = (w & 1) * 64;
    int ty = lane >> 3, tx = lane & 7;
    int r0 = qr + ty * 8, c0 = qc + tx * 8;
    float acc[8][8] = {};

    __syncthreads();

    for (int kt = 0; kt < 256; kt += 16) {
        float sh = Ss[arow * 8 + (kt >> 5)];
#pragma unroll
        for (int j = 0; j < 8; ++j) {
            int kk = kgrp + j;
            float a = fmaxf(fmaf(sh, w1s[kt + kk], b1s[kt + kk]), 0.f);
            Ast[kk][arow] = rowvalid ? a : 0.f;
        }
        const float* bg = Bbase + (size_t)(kt + brow) * 256 + bcol;
        *(float4*)&Bs[brow][bcol] = *(const float4*)bg;
        *(float4*)&Bs[brow][bcol + 4] = *(const float4*)(bg + 4);
        __syncthreads();
#pragma unroll
        for (int kk = 0; kk < 16; ++kk) {
            float4 a0 = *(const float4*)&Ast[kk][r0];
            float4 a1 = *(const float4*)&Ast[kk][r0 + 4];
            float4 b0 = *(const float4*)&Bs[kk][c0];
            float4 b1v = *(const float4*)&Bs[kk][c0 + 4];
            float ar[8] = {a0.x, a0.y, a0.z, a0.w, a1.x, a1.y, a1.z, a1.w};
            float br[8] = {b0.x, b0.y, b0.z, b0.w, b1v.x, b1v.y, b1v.z, b1v.w};
#pragma unroll
            for (int i2 = 0; i2 < 8; ++i2)
#pragma unroll
                for (int j2 = 0; j2 < 8; ++j2) acc[i2][j2] += ar[i2] * br[j2];
        }
        __syncthreads();
    }
#pragma unroll
    for (int i2 = 0; i2 < 8; ++i2) {
        int gm = bm * 128 + r0 + i2;
        if (gm < M) {
            float4 pack;
            ((__half2*)&pack)[0] = __floats2half2_rn(acc[i2][0], acc[i2][1]);
            ((__half2*)&pack)[1] = __floats2half2_rn(acc[i2][2], acc[i2][3]);
            ((__half2*)&pack)[2] = __floats2half2_rn(acc[i2][4], acc[i2][5]);
            ((__half2*)&pack)[3] = __floats2half2_rn(acc[i2][6], acc[i2][7]);
            *(float4*)(C16 + (size_t)gm * 256 + bn * 128 + c0) = pack;
        }
    }
}

// ---------------- plain fp32 GEMM (fallback path) ----------------

__global__ __launch_bounds__(256) void gemm_kernel(const float* __restrict__ A,
                                                   const float* __restrict__ B,
                                                   float* __restrict__ C, int M) {
    __shared__ float Ast[8][132];
    __shared__ float Bs[8][128];
    int tid = threadIdx.x;
    int bm = blockIdx.x, bn = blockIdx.y;
    int ty = tid >> 4, tx = tid & 15;
    int r0 = ty * 8, c0 = tx * 8;
    float acc[8][8] = {};
    int arow = tid >> 1, acol = (tid & 1) * 4;
    int brow = tid >> 5, bcol = (tid & 31) * 4;
    const float* Bbase = B + bn * 128;

    for (int kt = 0; kt < 256; kt += 8) {
        int gr = bm * 128 + arow;
        float4 av = (gr < M) ? *(const float4*)(A + (size_t)gr * 256 + kt + acol)
                             : make_float4(0.f, 0.f, 0.f, 0.f);
        Ast[acol + 0][arow] = av.x;
        Ast[acol + 1][arow] = av.y;
        Ast[acol + 2][arow] = av.z;
        Ast[acol + 3][arow] = av.w;
        *(float4*)&Bs[brow][bcol] = *(const float4*)(Bbase + (size_t)(kt + brow) * 256 + bcol);
        __syncthreads();
#pragma unroll
        for (int kk = 0; kk < 8; ++kk) {
            float4 a0 = *(const float4*)&Ast[kk][r0];
            float4 a1 = *(const float4*)&Ast[kk][r0 + 4];
            float4 b0 = *(const float4*)&Bs[kk][c0];
            float4 b1 = *(const float4*)&Bs[kk][c0 + 4];
            float ar[8] = {a0.x, a0.y, a0.z, a0.w, a1.x, a1.y, a1.z, a1.w};
            float br[8] = {b0.x, b0.y, b0.z, b0.w, b1.x, b1.y, b1.z, b1.w};
#pragma unroll
            for (int i2 = 0; i2 < 8; ++i2)
#pragma unroll
                for (int j2 = 0; j2 < 8; ++j2) acc[i2][j2] += ar[i2] * br[j2];
        }
        __syncthreads();
    }
#pragma unroll
    for (int i2 = 0; i2 < 8; ++i2) {
        int gm = bm * 128 + r0 + i2;
        if (gm < M) {
            *(float4*)(C + (size_t)gm * 256 + bn * 128 + c0) =
                make_float4(acc[i2][0], acc[i2][1], acc[i2][2], acc[i2][3]);
            *(float4*)(C + (size_t)gm * 256 + bn * 128 + c0 + 4) =
                make_float4(acc[i2][4], acc[i2][5], acc[i2][6], acc[i2][7]);
        }
    }
}

// ---------------- merge f64 pool partials -> f32 emb; zero LSTM flags ----------------

__global__ void merge_kernel(const double* __restrict__ embp, float* __restrict__ emb,
                             int* __restrict__ flags) {
    int k = blockIdx.x, c = threadIdx.x;
    double s = 0.0;
#pragma unroll
    for (int p = 0; p < 32; ++p) s += embp[((size_t)k * 32 + p) * 256 + c];
    emb[k * 256 + c] = (float)s;
    if (blockIdx.x == 0 && threadIdx.x < 2 * (KSTEPS + 1)) flags[threadIdx.x] = 0;
}

// ---------------- bidirectional LSTM ----------------

__global__ __launch_bounds__(256) void lstm_rec_kernel(
    const float* __restrict__ emb, float invN,
    const float* __restrict__ Wih_f, const float* __restrict__ Whh_f,
    const float* __restrict__ bih_f, const float* __restrict__ bhh_f,
    const float* __restrict__ Wih_b, const float* __restrict__ Whh_b,
    const float* __restrict__ bih_b, const float* __restrict__ bhh_b,
    float* __restrict__ hbuf, int* __restrict__ flags, float* __restrict__ out) {
    int dir = blockIdx.x >> 4;
    int seg = blockIdx.x & 15;
    const float* Wih = dir ? Wih_b : Wih_f;
    const float* Whh = dir ? Whh_b : Whh_f;
    const float* bih = dir ? bih_b : bih_f;
    const float* bhh = dir ? bhh_b : bhh_f;

    __shared__ float wh[64 * 256];
    __shared__ float wi[64 * 256];
    __shared__ float xs_s[KSTEPS * 256];
    __shared__ float gx[KSTEPS][64];
    __shared__ float garr[64];
    __shared__ float hprev_s[256];
    int tid = threadIdx.x;

    for (int v = tid; v < 64 * 64; v += 256) {
        int lrow = v >> 6;
        int c4 = (v & 63) * 4;
        int grow = ((lrow >> 4) << 8) + seg * 16 + (lrow & 15);
        *(float4*)&wh[lrow * 256 + c4] = *(const float4*)(Whh + (size_t)grow * 256 + c4);
        *(float4*)&wi[lrow * 256 + c4] = *(const float4*)(Wih + (size_t)grow * 256 + c4);
    }
    for (int idx = tid; idx < KSTEPS * 256; idx += 256) xs_s[idx] = emb[idx] * invN;
    __syncthreads();

    for (int d = tid; d < KSTEPS * 64; d += 256) {
        int st = d >> 6, lr = d & 63;
        const float* wr = &wi[lr << 8];
        const float* xr = &xs_s[st << 8];
        int r = (tid & 63) << 2;
        float acc = 0.f;
#pragma unroll 8
        for (int kk = 0; kk < 256; kk += 4) {
            int k2 = (kk + r) & 255;
            acc += wr[k2] * xr[k2] + wr[k2 + 1] * xr[k2 + 1] +
                   wr[k2 + 2] * xr[k2 + 2] + wr[k2 + 3] * xr[k2 + 3];
        }
        int grow = ((lr >> 4) << 8) + seg * 16 + (lr & 15);
        gx[st][lr] = acc + bih[grow] + bhh[grow];
    }

    int* flag = flags + dir * (KSTEPS + 1);
    float* hb = hbuf + dir * (KSTEPS + 1) * 256;

    if (tid < 16)
        __hip_atomic_store(&hb[seg * 16 + tid], 0.f, __ATOMIC_RELAXED, __HIP_MEMORY_SCOPE_AGENT);
    __syncthreads();
    if (tid == 0)
        __hip_atomic_fetch_add(&flag[0], 1, __ATOMIC_RELEASE, __HIP_MEMORY_SCOPE_AGENT);

    float c_reg = 0.f;

    for (int step = 0; step < KSTEPS; ++step) {
        if (tid == 0) {
            while (__hip_atomic_load(&flag[step], __ATOMIC_RELAXED, __HIP_MEMORY_SCOPE_AGENT) < 16) {
                __builtin_amdgcn_s_sleep(1);
            }
            (void)__hip_atomic_load(&flag[step], __ATOMIC_ACQUIRE, __HIP_MEMORY_SCOPE_AGENT);
        }
        __syncthreads();
        hprev_s[tid] = __hip_atomic_load(&hb[step * 256 + tid], __ATOMIC_RELAXED,
                                         __HIP_MEMORY_SCOPE_AGENT);
        __syncthreads();

        int d = tid >> 2, p = tid & 3;
        const float* wr = &wh[(d << 8) + (p << 6)];
        const float* hr = &hprev_s[p << 6];
        int rot = tid & 63;
        float acc = 0.f;
#pragma unroll 8
        for (int k = 0; k < 64; ++k) {
            int k2 = (k + rot) & 63;
            acc += wr[k2] * hr[k2];
        }
        acc += __shfl_xor(acc, 1);
        acc += __shfl_xor(acc, 2);
        if (p == 0) garr[d] = acc;
        __syncthreads();

        if (tid < 16) {
            float ig = sigmoidf(garr[tid] + gx[step][tid]);
            float fg = sigmoidf(garr[16 + tid] + gx[step][16 + tid]);
            float gg = tanhf(garr[32 + tid] + gx[step][32 + tid]);
            float og = sigmoidf(garr[48 + tid] + gx[step][48 + tid]);
            float cn = fg * c_reg + ig * gg;
            c_reg = cn;
            float hn = og * tanhf(cn);
            __hip_atomic_store(&hb[(step + 1) * 256 + seg * 16 + tid], hn, __ATOMIC_RELAXED,
                               __HIP_MEMORY_SCOPE_AGENT);
        }
        __syncthreads();
        if (tid == 0)
            __hip_atomic_fetch_add(&flag[step + 1], 1, __ATOMIC_RELEASE, __HIP_MEMORY_SCOPE_AGENT);
    }

    if (tid < 16)
        out[dir * 256 + seg * 16 + tid] =
            __hip_atomic_load(&hb[KSTEPS * 256 + seg * 16 + tid], __ATOMIC_RELAXED,
                              __HIP_MEMORY_SCOPE_AGENT);
}

// ---------------- launch ----------------

extern "C" void kernel_launch(void* const* d_in, const int* in_sizes, int n_in,
                              void* d_out, int out_size, void* d_ws, size_t ws_size,
                              hipStream_t stream) {
    const float* xs = (const float*)d_in[0];
    const int* edge_index = (const int*)d_in[1];
    const float* W1 = (const float*)d_in[2];
    const float* a_src1 = (const float*)d_in[3];
    const float* a_dst1 = (const float*)d_in[4];
    const float* b1 = (const float*)d_in[5];
    const float* W2 = (const float*)d_in[6];
    const float* a_src2 = (const float*)d_in[7];
    const float* a_dst2 = (const float*)d_in[8];
    const float* b2 = (const float*)d_in[9];
    const float* Wih_f = (const float*)d_in[10];
    const float* Whh_f = (const float*)d_in[11];
    const float* bih_f = (const float*)d_in[12];
    const float* bhh_f = (const float*)d_in[13];
    const float* Wih_b = (const float*)d_in[14];
    const float* Whh_b = (const float*)d_in[15];
    const float* bih_b = (const float*)d_in[16];
    const float* bhh_b = (const float*)d_in[17];

    const int K = KSTEPS;
    int D1 = in_sizes[2] / D2;
    int N = in_sizes[0] / (K * D1);
    int E = in_sizes[1] / (2 * K);
    int E2 = E + N;

    auto al = [](size_t x) { return (x + 255) & ~(size_t)255; };
    size_t fixed_sz = al((size_t)K * N * 4)
                    + al((size_t)K * (N + 1) * 4)
                    + al((size_t)K * N * 4)
                    + al((size_t)K * E2 * 4)
                    + al((size_t)K * 32 * 256 * 8)
                    + al((size_t)K * 256 * 4)
                    + al((size_t)2 * (K + 1) * 256 * 4)
                    + al((size_t)2 * (K + 1) * 4)
                    + al(16 * 4);
    int BK = 8;
    while (BK > 1) {
        size_t need = fixed_sz + 3 * al((size_t)BK * N * 8 * 4) + 2 * al((size_t)BK * N * 256 * 4);
        if (need <= ws_size) break;
        BK >>= 1;
    }

    char* w = (char*)d_ws;
    auto alloc = [&](size_t bytes) { char* p = w; w += (bytes + 255) & ~(size_t)255; return p; };
    int* counts = (int*)alloc((size_t)K * N * 4);
    int* row_ptr = (int*)alloc((size_t)K * (N + 1) * 4);
    int* fill = (int*)alloc((size_t)K * N * 4);
    int* ein = (int*)alloc((size_t)K * E2 * 4);
    double* embp = (double*)alloc((size_t)K * 32 * 256 * 8);
    float* emb = (float*)alloc((size_t)K * 256 * 4);
    float* hbuf = (float*)alloc((size_t)2 * (K + 1) * 256 * 4);
    int* flags = (int*)alloc((size_t)2 * (K + 1) * 4);
    float* Pvec = (float*)alloc(16 * 4);
    float* Sbuf = (float*)alloc((size_t)BK * N * 8 * 4);
    float* s_src = (float*)alloc((size_t)BK * N * 8 * 4);
    float* s_dst = (float*)alloc((size_t)BK * N * 8 * 4);
    float* bufA = (float*)alloc((size_t)BK * N * 256 * 4);
    float* bufB = (float*)alloc((size_t)BK * N * 256 * 4);
    __half* h16 = (__half*)bufA;     // fast path
    __half* h16_fb = (__half*)bufB;  // fallback path

    int KN = K * N;
    int NEMBP = K * 32 * 256;
    int zblk = ((KN > NEMBP ? KN : NEMBP) + 255) / 256;
    zero_all_kernel<<<zblk, 256, 0, stream>>>(counts, fill, embp, KN, NEMBP,
                                              W1, a_src1, a_dst1, Pvec, D1);
    int eblk = (E2 + 255) / 256;
    count_all_kernel<<<eblk * K, 256, 0, stream>>>(edge_index, E, N, K, counts);
    scan_all_kernel<<<K, 1024, 0, stream>>>(counts, row_ptr, N);
    scatter_all_kernel<<<eblk * K, 256, 0, stream>>>(edge_index, E, N, K, row_ptr, fill, ein);

    int nblk4 = (N + 3) / 4;
    int sblk = (N * 8 + 255) / 256;
    for (int k0 = 0; k0 < K; k0 += BK) {
        int BKcur = (K - k0 < BK) ? (K - k0) : BK;
        if (D1 == 1) {
            agg1s_all_kernel<<<nblk4 * BKcur, 256, 0, stream>>>(
                xs, Pvec, row_ptr, ein, Sbuf, N, E2, k0, BKcur);
            int M = BKcur * N;
            gemm_fused_kernel<<<dim3((M + 127) / 128, 2), 256, 0, stream>>>(
                Sbuf, W1, b1, W2, h16, M);
            s_all_h16_kernel<<<dim3(sblk, BKcur), 256, 0, stream>>>(h16, a_src2, a_dst2,
                                                                    s_src, s_dst, N);
            agg2pool_kernel<<<nblk4 * BKcur, 256, 0, stream>>>(
                h16, s_src, s_dst, row_ptr, ein, b2, embp, N, E2, k0, BKcur);
        } else {
            for (int kk = 0; kk < BKcur; ++kk) {
                int k = k0 + kk;
                const float* xk = xs + (size_t)k * N * D1;
                h1_kernel<<<(N * 256 + 255) / 256, 256, 0, stream>>>(xk, W1, bufA, N, D1);
                s_all_kernel<<<dim3(sblk, 1), 256, 0, stream>>>(bufA, a_src1, a_dst1,
                                                                s_src, s_dst, N);
                agg2_out_kernel<<<nblk4, 256, 0, stream>>>(bufA, s_src, s_dst, row_ptr, ein,
                                                           b1, bufB, N, E2, k);
                gemm_kernel<<<dim3((N + 127) / 128, 2), 256, 0, stream>>>(bufB, W2, bufA, N);
                cvt_kernel<<<(N * 256 / 2 + 255) / 256, 256, 0, stream>>>(bufA, h16_fb, N * 256);
                s_all_h16_kernel<<<dim3(sblk, 1), 256, 0, stream>>>(h16_fb, a_src2, a_dst2,
                                                                    s_src, s_dst, N);
                agg2pool_kernel<<<nblk4, 256, 0, stream>>>(
                    h16_fb, s_src, s_dst, row_ptr, ein, b2, embp, N, E2, k, 1);
            }
        }
    }

    merge_kernel<<<K, 256, 0, stream>>>(embp, emb, flags);
    lstm_rec_kernel<<<32, 256, 0, stream>>>(emb, 1.f / (float)N,
                                            Wih_f, Whh_f, bih_f, bhh_f,
                                            Wih_b, Whh_b, bih_b, bhh_b,
                                            hbuf, flags, (float*)d_out);
}